// Round 17
// baseline (108.028 us; speedup 1.0000x reference)
//
#include <hip/hip_runtime.h>
#include <hip/hip_bf16.h>
#include <stdint.h>

// CapsuleLayer dynamic routing v17.
// R0: packed (i,l) K=32 dense GEMM (v16-proven, ~10us).
// R1/R2: REWRITTEN on mfma_f32_32x32x16_bf16: M=32 = 2j x 16k, N=32 b,
//   K=16 (l=8 real, half waste vs 3/4). Wave = 4 j via 2 MFMA/i; WG = 32 b
//   (grid 256 = 4 bg x 64 slices). C layout (m74/m101): col=lane&31,
//   row=(reg&3)+8*(reg>>2)+4*(lane>>5) -> k-reduce = 8 in-lane FMA +
//   ONE shfl_xor(32); the ds_swizzle xor16 on the v16 critical path is gone,
//   and each barrier/exchange covers 2x the batches.
// Vr recomputed from raw s (v15-proven); epilogue transpose + 64-contiguous
// atomics (v6-proven); ping-pong s0/s1/s2.

using fab  = __attribute__((ext_vector_type(8)))  short;  // 8 bf16 = 4 VGPR
using fcc  = __attribute__((ext_vector_type(4)))  float;  // 16x16 C
using fc16 = __attribute__((ext_vector_type(16))) float;  // 32x32 C

__device__ __forceinline__ uint32_t bfr(float f) {   // fp32 -> bf16 RTN-even
    uint32_t u = __float_as_uint(f);
    return (u + 0x7fffu + ((u >> 16) & 1u)) >> 16;
}

// W3[((i*32 + j)*16 + k)*8 + l] bf16 ; blocks < 576 also emit
// X2[(i*128 + b)*8 + l] bf16.
__global__ __launch_bounds__(256)
void prep(const float* __restrict__ W, const float* __restrict__ x,
          ushort* __restrict__ W3, ushort* __restrict__ X2)
{
    const int t = blockIdx.x * 256 + threadIdx.x;
    {
        const int k = t & 15, j = (t >> 4) & 31, i = t >> 9;
        const float* src = W + (((size_t)j * 1152 + i) * 16 + k) * 8;
        const float4 a = *reinterpret_cast<const float4*>(src);
        const float4 b = *reinterpret_cast<const float4*>(src + 4);
        uint4 o;
        o.x = bfr(a.x) | (bfr(a.y) << 16);
        o.y = bfr(a.z) | (bfr(a.w) << 16);
        o.z = bfr(b.x) | (bfr(b.y) << 16);
        o.w = bfr(b.z) | (bfr(b.w) << 16);
        *reinterpret_cast<uint4*>(W3 + (size_t)t * 8) = o;
    }
    if (t < 147456) {
        const int b = t & 127, i = t >> 7;
        const float* src = x + ((size_t)b * 1152 + i) * 8;
        const float4 a = *reinterpret_cast<const float4*>(src);
        const float4 bb = *reinterpret_cast<const float4*>(src + 4);
        uint4 o;
        o.x = bfr(a.x) | (bfr(a.y) << 16);
        o.y = bfr(a.z) | (bfr(a.w) << 16);
        o.z = bfr(bb.x) | (bfr(bb.y) << 16);
        o.w = bfr(bb.z) | (bfr(bb.w) << 16);
        *reinterpret_cast<uint4*>(X2 + (size_t)t * 8) = o;
    }
}

// ============ R0: packed (i,l) K=32 GEMM, no softmax, no barriers ==========
__global__ __launch_bounds__(512)
void caps_route0(const ushort* __restrict__ W3,
                 const ushort* __restrict__ X2,
                 float* __restrict__ sout)
{
    __shared__ float tr[8][1024];

    const int tid  = threadIdx.x;
    const int lane = tid & 63;
    const int w    = tid >> 6;
    const int bl   = lane & 15;
    const int kg   = lane >> 4;
    const int bg   = blockIdx.x >> 6;
    const int sl   = blockIdx.x & 63;
    const int i0   = sl * 18;
    const int b0   = bg * 16;

    fab zf;
    #pragma unroll
    for (int q = 0; q < 8; ++q) zf[q] = 0;

    auto loadAq = [&](int g, int t, bool ok) -> fab {
        return ok ? *reinterpret_cast<const fab*>(
                       W3 + (((size_t)(i0 + 4 * g + kg) * 32 + w * 4 + t) * 16 + bl) * 8)
                  : zf;
    };
    auto loadBq = [&](int g, bool ok) -> fab {
        return ok ? *reinterpret_cast<const fab*>(
                       X2 + ((size_t)(i0 + 4 * g + kg) * 128 + b0 + bl) * 8)
                  : zf;
    };

    fcc sacc[4];
    #pragma unroll
    for (int t = 0; t < 4; ++t)
        #pragma unroll
        for (int r = 0; r < 4; ++r) sacc[t][r] = 0.0f;

    fab Ac[4], An[4], Bc, Bn;
    #pragma unroll
    for (int t = 0; t < 4; ++t) Ac[t] = loadAq(0, t, true);
    Bc = loadBq(0, true);

    #pragma unroll
    for (int g = 0; g < 5; ++g) {
        if (g < 4) {
            const bool ok = (g + 1 < 4) | (kg < 2);
            #pragma unroll
            for (int t = 0; t < 4; ++t) An[t] = loadAq(g + 1, t, ok);
            Bn = loadBq(g + 1, ok);
        }
        #pragma unroll
        for (int t = 0; t < 4; ++t)
            sacc[t] = __builtin_amdgcn_mfma_f32_16x16x32_bf16(Ac[t], Bc, sacc[t], 0, 0, 0);
        if (g < 4) {
            #pragma unroll
            for (int t = 0; t < 4; ++t) Ac[t] = An[t];
            Bc = Bn;
        }
    }

    {
        float* ep = &tr[w][0];
        #pragma unroll
        for (int t = 0; t < 4; ++t)
            #pragma unroll
            for (int r = 0; r < 4; ++r) {
                const int off = t * 16 + kg * 4 + r;
                ep[off * 16 + (bl ^ (off & 15))] = sacc[t][r] * 0.03125f;
            }
        float* sg = sout + (size_t)b0 * 512 + w * 64;
        #pragma unroll
        for (int c = 0; c < 16; ++c) {
            const float v = ep[lane * 16 + (c ^ (lane & 15))];
            atomicAdd(&sg[(size_t)c * 512 + lane], v);
        }
    }
}

// ====== R1/R2: 32x32x16 MFMA (2j x 16k x 32b), in-lane k-reduce ======
template<int R>
__global__ __launch_bounds__(512)
void caps_route_sm(const ushort* __restrict__ W3,
                   const ushort* __restrict__ X2,
                   const float* __restrict__ s0,
                   const float* __restrict__ s1,
                   float* __restrict__ sout)
{
    __shared__ float pl[2][8][32];    // per-wave denom partials, dbuf (2KB)
    __shared__ float tr[8][2048];     // per-wave transpose buffers (64KB)

    const int tid  = threadIdx.x;
    const int lane = tid & 63;
    const int w    = tid >> 6;        // wave 0..7 -> j = w*4 .. w*4+3
    const int bc   = lane & 31;       // b col / A row
    const int h    = lane >> 5;       // K-half (h=1 lanes: zero K-slots)
    const bool lo  = (h == 0);
    const int bg   = blockIdx.x >> 6; // 0..3 (32 b per WG)
    const int sl   = blockIdx.x & 63;
    const int i0   = sl * 18;
    const int b0   = bg * 32;

    fab zf;
    #pragma unroll
    for (int q = 0; q < 8; ++q) zf[q] = 0;

    // A: 32x16 = rows (j2 = bc>>4, k = bc&15) of j-pair m; K-slots l=0..7
    auto loadA = [&](int i, int m) -> fab {
        return lo ? *reinterpret_cast<const fab*>(
                        W3 + (((size_t)i * 32 + w * 4 + m * 2 + (bc >> 4)) * 16
                              + (bc & 15)) * 8)
                  : zf;
    };
    auto loadB = [&](int i) -> fab {
        return lo ? *reinterpret_cast<const fab*>(
                        X2 + ((size_t)i * 128 + b0 + bc) * 8)
                  : zf;
    };

    // Vr[jj][s]: s=0..7 maps to k = (s>>2)*8 + 4h + (s&3)  (this lane's k's)
    float Vr[4][8];
    #pragma unroll
    for (int jj = 0; jj < 4; ++jj) {
        const size_t ro = ((size_t)(b0 + bc) * 32 + w * 4 + jj) * 16;
        const float4 a0 = *reinterpret_cast<const float4*>(s0 + ro + 4 * h);
        const float4 a1 = *reinterpret_cast<const float4*>(s0 + ro + 8 + 4 * h);
        float q = a0.x * a0.x + a0.y * a0.y + a0.z * a0.z + a0.w * a0.w
                + a1.x * a1.x + a1.y * a1.y + a1.z * a1.z + a1.w * a1.w;
        q += __shfl_xor(q, 32);       // partner half's 8 k's
        const float sc = q / ((1.0f + q) * sqrtf(q + 1e-7f)) * 1.44269504f;
        Vr[jj][0] = a0.x * sc; Vr[jj][1] = a0.y * sc;
        Vr[jj][2] = a0.z * sc; Vr[jj][3] = a0.w * sc;
        Vr[jj][4] = a1.x * sc; Vr[jj][5] = a1.y * sc;
        Vr[jj][6] = a1.z * sc; Vr[jj][7] = a1.w * sc;
        if (R == 2) {
            const float4 b0v = *reinterpret_cast<const float4*>(s1 + ro + 4 * h);
            const float4 b1v = *reinterpret_cast<const float4*>(s1 + ro + 8 + 4 * h);
            float q1 = b0v.x * b0v.x + b0v.y * b0v.y + b0v.z * b0v.z + b0v.w * b0v.w
                     + b1v.x * b1v.x + b1v.y * b1v.y + b1v.z * b1v.z + b1v.w * b1v.w;
            q1 += __shfl_xor(q1, 32);
            const float sc1 = q1 / ((1.0f + q1) * sqrtf(q1 + 1e-7f)) * 1.44269504f;
            Vr[jj][0] += b0v.x * sc1; Vr[jj][1] += b0v.y * sc1;
            Vr[jj][2] += b0v.z * sc1; Vr[jj][3] += b0v.w * sc1;
            Vr[jj][4] += b1v.x * sc1; Vr[jj][5] += b1v.y * sc1;
            Vr[jj][6] += b1v.z * sc1; Vr[jj][7] += b1v.w * sc1;
        }
    }

    fc16 sacc[2];
    #pragma unroll
    for (int m = 0; m < 2; ++m)
        #pragma unroll
        for (int r = 0; r < 16; ++r) sacc[m][r] = 0.0f;

    const fc16 cz16 = {0,0,0,0, 0,0,0,0, 0,0,0,0, 0,0,0,0};

    fab Ac[2], An[2], Bc, Bn;
    #pragma unroll
    for (int m = 0; m < 2; ++m) Ac[m] = loadA(i0, m);
    Bc = loadB(i0);

    for (int ii = 0; ii < 18; ++ii) {
        {
            int ip = i0 + ii + 1;
            if (ip > 1151) ip = 1151;           // last prefetch unused
            #pragma unroll
            for (int m = 0; m < 2; ++m) An[m] = loadA(ip, m);
            Bn = loadB(ip);
        }

        fc16 u[2];
        #pragma unroll
        for (int m = 0; m < 2; ++m)
            u[m] = __builtin_amdgcn_mfma_f32_32x32x16_bf16(Ac[m], Bc, cz16, 0, 0, 0);

        // logits: 8 in-lane FMA + ONE shfl_xor(32) per (b, j)
        float e[4];
        float esum = 0.0f;
        #pragma unroll
        for (int m = 0; m < 2; ++m)
            #pragma unroll
            for (int j2 = 0; j2 < 2; ++j2) {
                const int jj = m * 2 + j2;
                float p = u[m][j2 * 8 + 0] * Vr[jj][0];
                #pragma unroll
                for (int s = 1; s < 8; ++s)
                    p = fmaf(u[m][j2 * 8 + s], Vr[jj][s], p);
                p += __shfl_xor(p, 32);         // other k-half
                e[jj] = exp2f(p);               // no max-subtract: |p| small
                esum += e[jj];
            }

        const int ib = ii & 1;
        if (h == 0) pl[ib][w][bc] = esum;
        __syncthreads();
        float den = pl[ib][0][bc];
        #pragma unroll
        for (int ww = 1; ww < 8; ++ww) den += pl[ib][ww][bc];
        const float inv = __builtin_amdgcn_rcpf(den);

        #pragma unroll
        for (int m = 0; m < 2; ++m)
            #pragma unroll
            for (int r = 0; r < 16; ++r)
                sacc[m][r] = fmaf(e[m * 2 + (r >> 3)] * inv, u[m][r], sacc[m][r]);

        #pragma unroll
        for (int m = 0; m < 2; ++m) Ac[m] = An[m];
        Bc = Bn;
    }

    // ---- epilogue: per-wave LDS transpose -> 64-contiguous atomics ----
    // value (m, r) = s[b0+bc][j = w*4 + m*2 + (r>>3)][k = (r&3)+8*((r>>2)&1)+4h]
    {
        float* ep = &tr[w][0];
        #pragma unroll
        for (int m = 0; m < 2; ++m)
            #pragma unroll
            for (int r = 0; r < 16; ++r) {
                const int off = (m * 2 + (r >> 3)) * 16
                              + (r & 3) + 8 * ((r >> 2) & 1) + 4 * h;
                ep[off * 32 + (bc ^ (off & 31))] = sacc[m][r];
            }
        float* sg = sout + (size_t)b0 * 512 + w * 64;
        #pragma unroll
        for (int c = 0; c < 32; ++c) {
            const float v = ep[lane * 32 + (c ^ (lane & 31))];
            atomicAdd(&sg[(size_t)c * 512 + lane], v);   // 64 contiguous
        }
    }
}

// out = squash(s2)
__global__ __launch_bounds__(256)
void caps_squash_out(const float* __restrict__ s2, float* __restrict__ out)
{
    const int t = blockIdx.x * 256 + threadIdx.x;
    const float sv = s2[t];
    float p = sv * sv;
    p += __shfl_xor(p, 1);
    p += __shfl_xor(p, 2);
    p += __shfl_xor(p, 4);
    p += __shfl_xor(p, 8);
    const float scale = p / ((1.0f + p) * sqrtf(p + 1e-7f));
    out[t] = scale * sv;
}

// ==================== fp32 fallback route (v6 verbatim) ====================
#define WJ        (1152 * 128)
#define I_TILE_F  24
#define NSLICE_F  48

template<int R>
__global__ __launch_bounds__(256)
void caps_route_f32(const float* __restrict__ x,
                    const float* __restrict__ W,
                    const float* __restrict__ Vacc,
                    float* __restrict__ s)
{
    __shared__ float Wt[2][4096];
    __shared__ float xs[8 * 192];

    const int tid  = threadIdx.x;
    const int lane = tid & 63;
    const int wv   = tid >> 6;
    const int j    = lane & 31;
    const int kh   = lane >> 5;
    const int bg   = blockIdx.x / NSLICE_F;
    const int sl   = blockIdx.x % NSLICE_F;
    const int i0   = sl * I_TILE_F;
    const int b0   = bg * 8 + wv * 2;

    const float* wsrc[4];
    #pragma unroll
    for (int t = 0; t < 4; ++t) {
        const int q  = (wv * 4 + t) * 1024 + lane * 16;
        const int rr = q >> 8;
        const int cb = (q & 255) ^ ((rr & 15) << 4);
        const int js = rr & 31;
        const int c  = (rr >> 5) * 64 + (cb >> 2);
        wsrc[t] = W + (size_t)js * WJ + c;
    }

    auto stage = [&](int buf, int i) {
        #pragma unroll
        for (int t = 0; t < 4; ++t)
            __builtin_amdgcn_global_load_lds(
                (const __attribute__((address_space(1))) uint32_t*)
                    (wsrc[t] + (size_t)i * 128),
                (__attribute__((address_space(3))) uint32_t*)
                    &Wt[buf][(wv * 4 + t) * 256], 16, 0, 0);
    };

    stage(0, i0);

    for (int cf = tid; cf < 384; cf += 256) {
        const int bl = cf / 48;
        const int rm = cf - bl * 48;
        float4 v = *reinterpret_cast<const float4*>(
            x + ((size_t)(bg * 8 + bl) * 1152 + i0) * 8 + rm * 4);
        *reinterpret_cast<float4*>(xs + bl * 192 + rm * 4) = v;
    }

    float Vr[2][8];
    if (R > 0) {
        #pragma unroll
        for (int bb = 0; bb < 2; ++bb) {
            const float* vp = Vacc + ((size_t)(b0 + bb) * 32 + j) * 16 + kh * 8;
            const float4 va = *reinterpret_cast<const float4*>(vp);
            const float4 vb = *reinterpret_cast<const float4*>(vp + 4);
            Vr[bb][0] = va.x * 1.44269504f; Vr[bb][1] = va.y * 1.44269504f;
            Vr[bb][2] = va.z * 1.44269504f; Vr[bb][3] = va.w * 1.44269504f;
            Vr[bb][4] = vb.x * 1.44269504f; Vr[bb][5] = vb.y * 1.44269504f;
            Vr[bb][6] = vb.z * 1.44269504f; Vr[bb][7] = vb.w * 1.44269504f;
        }
    }

    float sacc[2][8];
    #pragma unroll
    for (int bb = 0; bb < 2; ++bb)
        #pragma unroll
        for (int kk = 0; kk < 8; ++kk) sacc[bb][kk] = 0.0f;

    __syncthreads();

    const int sw = (j & 15) << 4;

    for (int ii = 0; ii < I_TILE_F; ++ii) {
        const int cur = ii & 1;
        if (ii + 1 < I_TILE_F) stage(cur ^ 1, i0 + ii + 1);

        float4 xa[2], xb[2];
        #pragma unroll
        for (int bb = 0; bb < 2; ++bb) {
            const float* xp = xs + (wv * 2 + bb) * 192 + ii * 8;
            xa[bb] = *reinterpret_cast<const float4*>(xp);
            xb[bb] = *reinterpret_cast<const float4*>(xp + 4);
        }

        const char* lbase = reinterpret_cast<const char*>(&Wt[cur][0]) + lane * 256;

        float u[2][8];
        #pragma unroll
        for (int kk = 0; kk < 8; ++kk) {
            const float4 w0 = *reinterpret_cast<const float4*>(lbase + ((kk * 32) ^ sw));
            const float4 w1 = *reinterpret_cast<const float4*>(lbase + ((kk * 32 + 16) ^ sw));
            #pragma unroll
            for (int bb = 0; bb < 2; ++bb) {
                float acc;
                acc = w0.x * xa[bb].x;
                acc = fmaf(w0.y, xa[bb].y, acc);
                acc = fmaf(w0.z, xa[bb].z, acc);
                acc = fmaf(w0.w, xa[bb].w, acc);
                acc = fmaf(w1.x, xb[bb].x, acc);
                acc = fmaf(w1.y, xb[bb].y, acc);
                acc = fmaf(w1.z, xb[bb].z, acc);
                acc = fmaf(w1.w, xb[bb].w, acc);
                u[bb][kk] = acc;
            }
        }

        if (R == 0) {
            #pragma unroll
            for (int bb = 0; bb < 2; ++bb)
                #pragma unroll
                for (int kk = 0; kk < 8; ++kk)
                    sacc[bb][kk] = fmaf(0.03125f, u[bb][kk], sacc[bb][kk]);
        } else {
            float p0 = u[0][0] * Vr[0][0];
            float p1 = u[1][0] * Vr[1][0];
            #pragma unroll
            for (int kk = 1; kk < 8; ++kk) {
                p0 = fmaf(u[0][kk], Vr[0][kk], p0);
                p1 = fmaf(u[1][kk], Vr[1][kk], p1);
            }
            p0 += __shfl_xor(p0, 32);
            p1 += __shfl_xor(p1, 32);
            const float pq = kh ? p1 : p0;
            const float e  = exp2f(pq);
            float den = e;
            den += __shfl_xor(den, 1);
            den += __shfl_xor(den, 2);
            den += __shfl_xor(den, 4);
            den += __shfl_xor(den, 8);
            den += __shfl_xor(den, 16);
            const float cf_own = e * __builtin_amdgcn_rcpf(den);
            const float cf_oth = __shfl_xor(cf_own, 32);
            const float cf0 = kh ? cf_oth : cf_own;
            const float cf1 = kh ? cf_own : cf_oth;
            #pragma unroll
            for (int kk = 0; kk < 8; ++kk) {
                sacc[0][kk] = fmaf(cf0, u[0][kk], sacc[0][kk]);
                sacc[1][kk] = fmaf(cf1, u[1][kk], sacc[1][kk]);
            }
        }
        __syncthreads();
    }

    {
        float* ep = &Wt[0][0] + wv * 1024;
        #pragma unroll
        for (int bb = 0; bb < 2; ++bb)
            #pragma unroll
            for (int kk = 0; kk < 8; ++kk)
                ep[bb * 512 + j * 16 + ((kh * 8 + kk) ^ ((j >> 1) & 15))] =
                    sacc[bb][kk];

        float* sg = s + (size_t)b0 * 512;
        #pragma unroll
        for (int c = 0; c < 16; ++c) {
            const int m   = c * 64 + lane;
            const int bb2 = m >> 9;
            const int j2  = (m >> 4) & 31;
            const int k2  = m & 15;
            const float v = ep[bb2 * 512 + j2 * 16 + (k2 ^ ((j2 >> 1) & 15))];
            atomicAdd(&sg[m], v);
        }
    }
}

// Fallback squash. MODE 0: Vacc = v, zero s; 1: Vacc += v, zero s; 2: out = v
template<int MODE>
__global__ __launch_bounds__(256)
void caps_squash(float* __restrict__ s,
                 float* __restrict__ Vacc,
                 float* __restrict__ out)
{
    const int t = blockIdx.x * 256 + threadIdx.x;
    const float sv = s[t];
    float p = sv * sv;
    p += __shfl_xor(p, 1);
    p += __shfl_xor(p, 2);
    p += __shfl_xor(p, 4);
    p += __shfl_xor(p, 8);
    const float scale = p / ((1.0f + p) * sqrtf(p + 1e-7f));
    const float v = scale * sv;
    if (MODE == 0)      { Vacc[t] = v;  s[t] = 0.0f; }
    else if (MODE == 1) { Vacc[t] += v; s[t] = 0.0f; }
    else                { out[t] = v; }
}

extern "C" void kernel_launch(void* const* d_in, const int* in_sizes, int n_in,
                              void* d_out, int out_size, void* d_ws, size_t ws_size,
                              hipStream_t stream)
{
    const float* x = (const float*)d_in[0];   // [128,1152,8]
    const float* W = (const float*)d_in[1];   // [32,1152,16,8]
    float* out = (float*)d_out;               // [128,32,16]

    const size_t W3B = (size_t)589824 * 16;   // 9,437,184 B
    const size_t X2B = (size_t)147456 * 16;   // 2,359,296 B
    const size_t SB  = (size_t)65536 * sizeof(float);   // 256 KB

    if (ws_size >= W3B + X2B + 3 * SB) {
        ushort* W3 = (ushort*)d_ws;
        ushort* X2 = (ushort*)((char*)d_ws + W3B);
        float* s0  = (float*)((char*)d_ws + W3B + X2B);
        float* s1  = s0 + 65536;
        float* s2  = s1 + 65536;

        hipMemsetAsync(s0, 0, 3 * SB, stream);
        prep<<<2304, 256, 0, stream>>>(W, x, W3, X2);

        caps_route0<<<512, 512, 0, stream>>>(W3, X2, s0);
        caps_route_sm<1><<<256, 512, 0, stream>>>(W3, X2, s0, s0, s1);
        caps_route_sm<2><<<256, 512, 0, stream>>>(W3, X2, s0, s1, s2);
        caps_squash_out<<<256, 256, 0, stream>>>(s2, out);
    } else {
        float* Vacc = (float*)d_ws;
        float* sbuf = Vacc + 65536;
        hipMemsetAsync(sbuf, 0, SB, stream);

        dim3 grid(16 * NSLICE_F);  // 768 WGs
        dim3 blk(256);
        caps_route_f32<0><<<grid, blk, 0, stream>>>(x, W, Vacc, sbuf);
        caps_squash<0><<<256, 256, 0, stream>>>(sbuf, Vacc, out);
        caps_route_f32<1><<<grid, blk, 0, stream>>>(x, W, Vacc, sbuf);
        caps_squash<1><<<256, 256, 0, stream>>>(sbuf, Vacc, out);
        caps_route_f32<2><<<grid, blk, 0, stream>>>(x, W, Vacc, sbuf);
        caps_squash<2><<<256, 256, 0, stream>>>(sbuf, Vacc, out);
    }
}

// Round 18
// 104.911 us; speedup vs baseline: 1.0297x; 1.0297x over previous
//
#include <hip/hip_runtime.h>
#include <hip/hip_bf16.h>
#include <stdint.h>

// CapsuleLayer dynamic routing v18 = v16 (best, 105.7us) + non-draining
// softmax barrier.
// R0: packed (i,l) K=32 dense GEMM (v16-proven, ~10us).
// R1/R2: 16x16x32 MFMA + pair-softmax. v16/v17 showed the exchange ARITHMETIC
// is not the cost; the remaining suspect is that __syncthreads() emits
// s_waitcnt vmcnt(0) before s_barrier, force-draining the i+1 register
// prefetches 9x per kernel -> full L2/L3 latency (W3 9.4MB > 4MB XCD L2)
// exposed per iteration. v18: s_waitcnt lgkmcnt(0) (LDS visibility only) +
// raw s_barrier; global loads stay in flight across the barrier (compiler
// inserts its own vmcnt before the A/B consumption).
// pl[pp&1] double-buffer makes one-barrier-per-pair overrun-safe.

using fab = __attribute__((ext_vector_type(8))) short;   // 8 bf16 = 4 VGPR
using fcc = __attribute__((ext_vector_type(4))) float;   // 4 f32 accum

__device__ __forceinline__ uint32_t bfr(float f) {   // fp32 -> bf16 RTN-even
    uint32_t u = __float_as_uint(f);
    return (u + 0x7fffu + ((u >> 16) & 1u)) >> 16;
}

// W3[((i*32 + j)*16 + k)*8 + l] bf16 ; blocks < 576 also emit
// X2[(i*128 + b)*8 + l] bf16.
__global__ __launch_bounds__(256)
void prep(const float* __restrict__ W, const float* __restrict__ x,
          ushort* __restrict__ W3, ushort* __restrict__ X2)
{
    const int t = blockIdx.x * 256 + threadIdx.x;
    {
        const int k = t & 15, j = (t >> 4) & 31, i = t >> 9;
        const float* src = W + (((size_t)j * 1152 + i) * 16 + k) * 8;
        const float4 a = *reinterpret_cast<const float4*>(src);
        const float4 b = *reinterpret_cast<const float4*>(src + 4);
        uint4 o;
        o.x = bfr(a.x) | (bfr(a.y) << 16);
        o.y = bfr(a.z) | (bfr(a.w) << 16);
        o.z = bfr(b.x) | (bfr(b.y) << 16);
        o.w = bfr(b.z) | (bfr(b.w) << 16);
        *reinterpret_cast<uint4*>(W3 + (size_t)t * 8) = o;
    }
    if (t < 147456) {
        const int b = t & 127, i = t >> 7;
        const float* src = x + ((size_t)b * 1152 + i) * 8;
        const float4 a = *reinterpret_cast<const float4*>(src);
        const float4 bb = *reinterpret_cast<const float4*>(src + 4);
        uint4 o;
        o.x = bfr(a.x) | (bfr(a.y) << 16);
        o.y = bfr(a.z) | (bfr(a.w) << 16);
        o.z = bfr(bb.x) | (bfr(bb.y) << 16);
        o.w = bfr(bb.z) | (bfr(bb.w) << 16);
        *reinterpret_cast<uint4*>(X2 + (size_t)t * 8) = o;
    }
}

// ============ R0: packed (i,l) K=32 GEMM, no softmax, no barriers ==========
__global__ __launch_bounds__(512)
void caps_route0(const ushort* __restrict__ W3,
                 const ushort* __restrict__ X2,
                 float* __restrict__ sout)
{
    __shared__ float tr[8][1024];

    const int tid  = threadIdx.x;
    const int lane = tid & 63;
    const int w    = tid >> 6;
    const int bl   = lane & 15;
    const int kg   = lane >> 4;
    const int bg   = blockIdx.x >> 6;
    const int sl   = blockIdx.x & 63;
    const int i0   = sl * 18;
    const int b0   = bg * 16;

    fab zf;
    #pragma unroll
    for (int q = 0; q < 8; ++q) zf[q] = 0;

    auto loadAq = [&](int g, int t, bool ok) -> fab {
        return ok ? *reinterpret_cast<const fab*>(
                       W3 + (((size_t)(i0 + 4 * g + kg) * 32 + w * 4 + t) * 16 + bl) * 8)
                  : zf;
    };
    auto loadBq = [&](int g, bool ok) -> fab {
        return ok ? *reinterpret_cast<const fab*>(
                       X2 + ((size_t)(i0 + 4 * g + kg) * 128 + b0 + bl) * 8)
                  : zf;
    };

    fcc sacc[4];
    #pragma unroll
    for (int t = 0; t < 4; ++t)
        #pragma unroll
        for (int r = 0; r < 4; ++r) sacc[t][r] = 0.0f;

    fab Ac[4], An[4], Bc, Bn;
    #pragma unroll
    for (int t = 0; t < 4; ++t) Ac[t] = loadAq(0, t, true);
    Bc = loadBq(0, true);

    #pragma unroll
    for (int g = 0; g < 5; ++g) {
        if (g < 4) {
            const bool ok = (g + 1 < 4) | (kg < 2);
            #pragma unroll
            for (int t = 0; t < 4; ++t) An[t] = loadAq(g + 1, t, ok);
            Bn = loadBq(g + 1, ok);
        }
        #pragma unroll
        for (int t = 0; t < 4; ++t)
            sacc[t] = __builtin_amdgcn_mfma_f32_16x16x32_bf16(Ac[t], Bc, sacc[t], 0, 0, 0);
        if (g < 4) {
            #pragma unroll
            for (int t = 0; t < 4; ++t) Ac[t] = An[t];
            Bc = Bn;
        }
    }

    {
        float* ep = &tr[w][0];
        #pragma unroll
        for (int t = 0; t < 4; ++t)
            #pragma unroll
            for (int r = 0; r < 4; ++r) {
                const int off = t * 16 + kg * 4 + r;
                ep[off * 16 + (bl ^ (off & 15))] = sacc[t][r] * 0.03125f;
            }
        float* sg = sout + (size_t)b0 * 512 + w * 64;
        #pragma unroll
        for (int c = 0; c < 16; ++c) {
            const float v = ep[lane * 16 + (c ^ (lane & 15))];
            atomicAdd(&sg[(size_t)c * 512 + lane], v);
        }
    }
}

// ============ R1/R2: per-i MFMA + pair-softmax (1 barrier / 2 i) ===========
template<int R>
__global__ __launch_bounds__(512, 4)
void caps_route_sm(const ushort* __restrict__ W3,
                   const ushort* __restrict__ X2,
                   const float* __restrict__ s0,
                   const float* __restrict__ s1,
                   float* __restrict__ sout)
{
    __shared__ float pl[2][8][16][2];    // [pairbuf][w][b][even/odd]
    __shared__ float tr[8][1024];

    const int tid  = threadIdx.x;
    const int lane = tid & 63;
    const int w    = tid >> 6;
    const int bl   = lane & 15;
    const int kg   = lane >> 4;          // 0..3
    const bool lo  = (kg == 0);          // K-slots 0..7 real (l = 0..7)
    const int bg   = blockIdx.x >> 6;
    const int sl   = blockIdx.x & 63;
    const int i0   = sl * 18;
    const int b0   = bg * 16;

    fab zf;
    #pragma unroll
    for (int q = 0; q < 8; ++q) zf[q] = 0;

    auto loadA = [&](int i, int t) -> fab {
        return lo ? *reinterpret_cast<const fab*>(
                        W3 + (((size_t)i * 32 + w * 4 + t) * 16 + bl) * 8)
                  : zf;
    };
    auto loadB = [&](int i) -> fab {
        return lo ? *reinterpret_cast<const fab*>(
                        X2 + ((size_t)i * 128 + b0 + bl) * 8)
                  : zf;
    };

    // Vr = accumulated squash of prior rounds, recomputed from raw s
    float Vr[4][4];
    #pragma unroll
    for (int t = 0; t < 4; ++t) {
        const size_t ro = ((size_t)(b0 + bl) * 32 + w * 4 + t) * 16 + kg * 4;
        const float4 a = *reinterpret_cast<const float4*>(s0 + ro);
        float q = a.x * a.x + a.y * a.y + a.z * a.z + a.w * a.w;
        q += __shfl_xor(q, 16);
        q += __shfl_xor(q, 32);
        const float sc = q / ((1.0f + q) * sqrtf(q + 1e-7f)) * 1.44269504f;
        Vr[t][0] = a.x * sc; Vr[t][1] = a.y * sc;
        Vr[t][2] = a.z * sc; Vr[t][3] = a.w * sc;
        if (R == 2) {
            const float4 b = *reinterpret_cast<const float4*>(s1 + ro);
            float q1 = b.x * b.x + b.y * b.y + b.z * b.z + b.w * b.w;
            q1 += __shfl_xor(q1, 16);
            q1 += __shfl_xor(q1, 32);
            const float sc1 = q1 / ((1.0f + q1) * sqrtf(q1 + 1e-7f)) * 1.44269504f;
            Vr[t][0] += b.x * sc1; Vr[t][1] += b.y * sc1;
            Vr[t][2] += b.z * sc1; Vr[t][3] += b.w * sc1;
        }
    }

    fcc sacc[4];
    #pragma unroll
    for (int t = 0; t < 4; ++t)
        #pragma unroll
        for (int r = 0; r < 4; ++r) sacc[t][r] = 0.0f;

    const fcc cz = {0.0f, 0.0f, 0.0f, 0.0f};

    fab A0[4], A1[4], B0, B1;
    #pragma unroll
    for (int t = 0; t < 4; ++t) A0[t] = loadA(i0, t);
    B0 = loadB(i0);

    for (int pp = 0; pp < 9; ++pp) {
        const int ie = i0 + 2 * pp;
        // prefetch odd i
        #pragma unroll
        for (int t = 0; t < 4; ++t) A1[t] = loadA(ie + 1, t);
        B1 = loadB(ie + 1);

        // even i: MFMA + logits + exp (hold ue/ee across barrier)
        fcc ue[4];
        #pragma unroll
        for (int t = 0; t < 4; ++t)
            ue[t] = __builtin_amdgcn_mfma_f32_16x16x32_bf16(A0[t], B0, cz, 0, 0, 0);
        float ee[4], pse = 0.0f;
        #pragma unroll
        for (int t = 0; t < 4; ++t) {
            float p = ue[t][0] * Vr[t][0];
            p = fmaf(ue[t][1], Vr[t][1], p);
            p = fmaf(ue[t][2], Vr[t][2], p);
            p = fmaf(ue[t][3], Vr[t][3], p);
            p += __shfl_xor(p, 16);
            p += __shfl_xor(p, 32);
            ee[t] = exp2f(p);
            pse += ee[t];
        }
        if (lane < 16) pl[pp & 1][w][bl][0] = pse;

        // prefetch next even i
        if (pp < 8) {
            #pragma unroll
            for (int t = 0; t < 4; ++t) A0[t] = loadA(ie + 2, t);
            B0 = loadB(ie + 2);
        }

        // odd i: MFMA + logits + exp
        fcc uo[4];
        #pragma unroll
        for (int t = 0; t < 4; ++t)
            uo[t] = __builtin_amdgcn_mfma_f32_16x16x32_bf16(A1[t], B1, cz, 0, 0, 0);
        float eo[4], pso = 0.0f;
        #pragma unroll
        for (int t = 0; t < 4; ++t) {
            float p = uo[t][0] * Vr[t][0];
            p = fmaf(uo[t][1], Vr[t][1], p);
            p = fmaf(uo[t][2], Vr[t][2], p);
            p = fmaf(uo[t][3], Vr[t][3], p);
            p += __shfl_xor(p, 16);
            p += __shfl_xor(p, 32);
            eo[t] = exp2f(p);
            pso += eo[t];
        }
        if (lane >= 16 && lane < 32) pl[pp & 1][w][bl][1] = pso;

        // NON-DRAINING barrier: LDS visibility only; global prefetches for
        // the next pair stay in flight (no vmcnt(0) drain — the m218 lever).
        asm volatile("s_waitcnt lgkmcnt(0)" ::: "memory");
        __builtin_amdgcn_s_barrier();
        asm volatile("" ::: "memory");

        float dene = 0.0f, deno = 0.0f;
        #pragma unroll
        for (int ww = 0; ww < 8; ++ww) {
            const float2 d = *reinterpret_cast<const float2*>(&pl[pp & 1][ww][bl][0]);
            dene += d.x;
            deno += d.y;
        }
        const float inve = __builtin_amdgcn_rcpf(dene);
        const float invo = __builtin_amdgcn_rcpf(deno);
        #pragma unroll
        for (int t = 0; t < 4; ++t) {
            const float cfe = ee[t] * inve;
            const float cfo = eo[t] * invo;
            #pragma unroll
            for (int r = 0; r < 4; ++r) {
                sacc[t][r] = fmaf(cfe, ue[t][r], sacc[t][r]);
                sacc[t][r] = fmaf(cfo, uo[t][r], sacc[t][r]);
            }
        }
    }

    // epilogue: per-wave LDS transpose -> 64-contiguous atomics
    {
        float* ep = &tr[w][0];
        #pragma unroll
        for (int t = 0; t < 4; ++t)
            #pragma unroll
            for (int r = 0; r < 4; ++r) {
                const int off = t * 16 + kg * 4 + r;
                ep[off * 16 + (bl ^ (off & 15))] = sacc[t][r];
            }
        float* sg = sout + (size_t)b0 * 512 + w * 64;
        #pragma unroll
        for (int c = 0; c < 16; ++c) {
            const float v = ep[lane * 16 + (c ^ (lane & 15))];
            atomicAdd(&sg[(size_t)c * 512 + lane], v);
        }
    }
}

// out = squash(s2)
__global__ __launch_bounds__(256)
void caps_squash_out(const float* __restrict__ s2, float* __restrict__ out)
{
    const int t = blockIdx.x * 256 + threadIdx.x;
    const float sv = s2[t];
    float p = sv * sv;
    p += __shfl_xor(p, 1);
    p += __shfl_xor(p, 2);
    p += __shfl_xor(p, 4);
    p += __shfl_xor(p, 8);
    const float scale = p / ((1.0f + p) * sqrtf(p + 1e-7f));
    out[t] = scale * sv;
}

// ==================== fp32 fallback route (v6 verbatim) ====================
#define WJ        (1152 * 128)
#define I_TILE_F  24
#define NSLICE_F  48

template<int R>
__global__ __launch_bounds__(256)
void caps_route_f32(const float* __restrict__ x,
                    const float* __restrict__ W,
                    const float* __restrict__ Vacc,
                    float* __restrict__ s)
{
    __shared__ float Wt[2][4096];
    __shared__ float xs[8 * 192];

    const int tid  = threadIdx.x;
    const int lane = tid & 63;
    const int wv   = tid >> 6;
    const int j    = lane & 31;
    const int kh   = lane >> 5;
    const int bg   = blockIdx.x / NSLICE_F;
    const int sl   = blockIdx.x % NSLICE_F;
    const int i0   = sl * I_TILE_F;
    const int b0   = bg * 8 + wv * 2;

    const float* wsrc[4];
    #pragma unroll
    for (int t = 0; t < 4; ++t) {
        const int q  = (wv * 4 + t) * 1024 + lane * 16;
        const int rr = q >> 8;
        const int cb = (q & 255) ^ ((rr & 15) << 4);
        const int js = rr & 31;
        const int c  = (rr >> 5) * 64 + (cb >> 2);
        wsrc[t] = W + (size_t)js * WJ + c;
    }

    auto stage = [&](int buf, int i) {
        #pragma unroll
        for (int t = 0; t < 4; ++t)
            __builtin_amdgcn_global_load_lds(
                (const __attribute__((address_space(1))) uint32_t*)
                    (wsrc[t] + (size_t)i * 128),
                (__attribute__((address_space(3))) uint32_t*)
                    &Wt[buf][(wv * 4 + t) * 256], 16, 0, 0);
    };

    stage(0, i0);

    for (int cf = tid; cf < 384; cf += 256) {
        const int bl = cf / 48;
        const int rm = cf - bl * 48;
        float4 v = *reinterpret_cast<const float4*>(
            x + ((size_t)(bg * 8 + bl) * 1152 + i0) * 8 + rm * 4);
        *reinterpret_cast<float4*>(xs + bl * 192 + rm * 4) = v;
    }

    float Vr[2][8];
    if (R > 0) {
        #pragma unroll
        for (int bb = 0; bb < 2; ++bb) {
            const float* vp = Vacc + ((size_t)(b0 + bb) * 32 + j) * 16 + kh * 8;
            const float4 va = *reinterpret_cast<const float4*>(vp);
            const float4 vb = *reinterpret_cast<const float4*>(vp + 4);
            Vr[bb][0] = va.x * 1.44269504f; Vr[bb][1] = va.y * 1.44269504f;
            Vr[bb][2] = va.z * 1.44269504f; Vr[bb][3] = va.w * 1.44269504f;
            Vr[bb][4] = vb.x * 1.44269504f; Vr[bb][5] = vb.y * 1.44269504f;
            Vr[bb][6] = vb.z * 1.44269504f; Vr[bb][7] = vb.w * 1.44269504f;
        }
    }

    float sacc[2][8];
    #pragma unroll
    for (int bb = 0; bb < 2; ++bb)
        #pragma unroll
        for (int kk = 0; kk < 8; ++kk) sacc[bb][kk] = 0.0f;

    __syncthreads();

    const int sw = (j & 15) << 4;

    for (int ii = 0; ii < I_TILE_F; ++ii) {
        const int cur = ii & 1;
        if (ii + 1 < I_TILE_F) stage(cur ^ 1, i0 + ii + 1);

        float4 xa[2], xb[2];
        #pragma unroll
        for (int bb = 0; bb < 2; ++bb) {
            const float* xp = xs + (wv * 2 + bb) * 192 + ii * 8;
            xa[bb] = *reinterpret_cast<const float4*>(xp);
            xb[bb] = *reinterpret_cast<const float4*>(xp + 4);
        }

        const char* lbase = reinterpret_cast<const char*>(&Wt[cur][0]) + lane * 256;

        float u[2][8];
        #pragma unroll
        for (int kk = 0; kk < 8; ++kk) {
            const float4 w0 = *reinterpret_cast<const float4*>(lbase + ((kk * 32) ^ sw));
            const float4 w1 = *reinterpret_cast<const float4*>(lbase + ((kk * 32 + 16) ^ sw));
            #pragma unroll
            for (int bb = 0; bb < 2; ++bb) {
                float acc;
                acc = w0.x * xa[bb].x;
                acc = fmaf(w0.y, xa[bb].y, acc);
                acc = fmaf(w0.z, xa[bb].z, acc);
                acc = fmaf(w0.w, xa[bb].w, acc);
                acc = fmaf(w1.x, xb[bb].x, acc);
                acc = fmaf(w1.y, xb[bb].y, acc);
                acc = fmaf(w1.z, xb[bb].z, acc);
                acc = fmaf(w1.w, xb[bb].w, acc);
                u[bb][kk] = acc;
            }
        }

        if (R == 0) {
            #pragma unroll
            for (int bb = 0; bb < 2; ++bb)
                #pragma unroll
                for (int kk = 0; kk < 8; ++kk)
                    sacc[bb][kk] = fmaf(0.03125f, u[bb][kk], sacc[bb][kk]);
        } else {
            float p0 = u[0][0] * Vr[0][0];
            float p1 = u[1][0] * Vr[1][0];
            #pragma unroll
            for (int kk = 1; kk < 8; ++kk) {
                p0 = fmaf(u[0][kk], Vr[0][kk], p0);
                p1 = fmaf(u[1][kk], Vr[1][kk], p1);
            }
            p0 += __shfl_xor(p0, 32);
            p1 += __shfl_xor(p1, 32);
            const float pq = kh ? p1 : p0;
            const float e  = exp2f(pq);
            float den = e;
            den += __shfl_xor(den, 1);
            den += __shfl_xor(den, 2);
            den += __shfl_xor(den, 4);
            den += __shfl_xor(den, 8);
            den += __shfl_xor(den, 16);
            const float cf_own = e * __builtin_amdgcn_rcpf(den);
            const float cf_oth = __shfl_xor(cf_own, 32);
            const float cf0 = kh ? cf_oth : cf_own;
            const float cf1 = kh ? cf_own : cf_oth;
            #pragma unroll
            for (int kk = 0; kk < 8; ++kk) {
                sacc[0][kk] = fmaf(cf0, u[0][kk], sacc[0][kk]);
                sacc[1][kk] = fmaf(cf1, u[1][kk], sacc[1][kk]);
            }
        }
        __syncthreads();
    }

    {
        float* ep = &Wt[0][0] + wv * 1024;
        #pragma unroll
        for (int bb = 0; bb < 2; ++bb)
            #pragma unroll
            for (int kk = 0; kk < 8; ++kk)
                ep[bb * 512 + j * 16 + ((kh * 8 + kk) ^ ((j >> 1) & 15))] =
                    sacc[bb][kk];

        float* sg = s + (size_t)b0 * 512;
        #pragma unroll
        for (int c = 0; c < 16; ++c) {
            const int m   = c * 64 + lane;
            const int bb2 = m >> 9;
            const int j2  = (m >> 4) & 31;
            const int k2  = m & 15;
            const float v = ep[bb2 * 512 + j2 * 16 + (k2 ^ ((j2 >> 1) & 15))];
            atomicAdd(&sg[m], v);
        }
    }
}

// Fallback squash. MODE 0: Vacc = v, zero s; 1: Vacc += v, zero s; 2: out = v
template<int MODE>
__global__ __launch_bounds__(256)
void caps_squash(float* __restrict__ s,
                 float* __restrict__ Vacc,
                 float* __restrict__ out)
{
    const int t = blockIdx.x * 256 + threadIdx.x;
    const float sv = s[t];
    float p = sv * sv;
    p += __shfl_xor(p, 1);
    p += __shfl_xor(p, 2);
    p += __shfl_xor(p, 4);
    p += __shfl_xor(p, 8);
    const float scale = p / ((1.0f + p) * sqrtf(p + 1e-7f));
    const float v = scale * sv;
    if (MODE == 0)      { Vacc[t] = v;  s[t] = 0.0f; }
    else if (MODE == 1) { Vacc[t] += v; s[t] = 0.0f; }
    else                { out[t] = v; }
}

extern "C" void kernel_launch(void* const* d_in, const int* in_sizes, int n_in,
                              void* d_out, int out_size, void* d_ws, size_t ws_size,
                              hipStream_t stream)
{
    const float* x = (const float*)d_in[0];   // [128,1152,8]
    const float* W = (const float*)d_in[1];   // [32,1152,16,8]
    float* out = (float*)d_out;               // [128,32,16]

    const size_t W3B = (size_t)589824 * 16;   // 9,437,184 B
    const size_t X2B = (size_t)147456 * 16;   // 2,359,296 B
    const size_t SB  = (size_t)65536 * sizeof(float);   // 256 KB

    if (ws_size >= W3B + X2B + 3 * SB) {
        ushort* W3 = (ushort*)d_ws;
        ushort* X2 = (ushort*)((char*)d_ws + W3B);
        float* s0  = (float*)((char*)d_ws + W3B + X2B);
        float* s1  = s0 + 65536;
        float* s2  = s1 + 65536;

        hipMemsetAsync(s0, 0, 3 * SB, stream);
        prep<<<2304, 256, 0, stream>>>(W, x, W3, X2);

        caps_route0<<<512, 512, 0, stream>>>(W3, X2, s0);
        caps_route_sm<1><<<512, 512, 0, stream>>>(W3, X2, s0, s0, s1);
        caps_route_sm<2><<<512, 512, 0, stream>>>(W3, X2, s0, s1, s2);
        caps_squash_out<<<256, 256, 0, stream>>>(s2, out);
    } else {
        float* Vacc = (float*)d_ws;
        float* sbuf = Vacc + 65536;
        hipMemsetAsync(sbuf, 0, SB, stream);

        dim3 grid(16 * NSLICE_F);  // 768 WGs
        dim3 blk(256);
        caps_route_f32<0><<<grid, blk, 0, stream>>>(x, W, Vacc, sbuf);
        caps_squash<0><<<256, 256, 0, stream>>>(sbuf, Vacc, out);
        caps_route_f32<1><<<grid, blk, 0, stream>>>(x, W, Vacc, sbuf);
        caps_squash<1><<<256, 256, 0, stream>>>(sbuf, Vacc, out);
        caps_route_f32<2><<<grid, blk, 0, stream>>>(x, W, Vacc, sbuf);
        caps_squash<2><<<256, 256, 0, stream>>>(sbuf, Vacc, out);
    }
}